// Round 1
// baseline (141.015 us; speedup 1.0000x reference)
//
#include <hip/hip_runtime.h>
#include <hip/hip_bf16.h>

// ScaledDotProductAttention: B=4, S=4096, D=64, fp32 in/out.
// scores = Q@K^T / 8; softmax; out = weights @ K  (K, not V -- per reference).
// bf16-MFMA flash attention, fp32 accumulate, swapped-operand orientation.

#define SQ   4096
#define DH   64
#define NB   4
#define QBLK 64     // q rows per block = 4 waves x 16
#define KBLK 64     // k rows per LDS tile
#define KS_STRIDE 72   // bf16 elems; 144B row: 16B-aligned, bank-spread
#define PS_STRIDE 72
#define OS_STRIDE 68   // fp32 elems; 272B row

typedef __bf16 bf16x8 __attribute__((ext_vector_type(8)));
typedef float  f32x4  __attribute__((ext_vector_type(4)));

union LdsU {
  struct {
    unsigned short Ks [KBLK][KS_STRIDE];   // K[k][d]   bf16
    unsigned short Kts[DH  ][KS_STRIDE];   // K^T[d][k] bf16
    unsigned short Ps [4][16][PS_STRIDE];  // per-wave P[q][k] bf16
  } s;
  float Osc[4][16][OS_STRIDE];             // epilogue transpose scratch
};

__device__ __forceinline__ unsigned short f2bf(float f) {
  return __builtin_bit_cast(unsigned short, (__bf16)f);
}

__global__ __launch_bounds__(256, 1)
void attn_fwd(const float* __restrict__ Qg, const float* __restrict__ Kg,
              float* __restrict__ Og) {
  __shared__ LdsU lds;
  const int tid  = threadIdx.x;
  const int wave = tid >> 6;
  const int lane = tid & 63;
  const int g    = lane >> 4;   // 16-lane group 0..3
  const int c    = lane & 15;

  const int batch = blockIdx.x / (SQ / QBLK);
  const int qt    = blockIdx.x % (SQ / QBLK);
  const int q0    = qt * QBLK + wave * 16;

  // ---- Q fragments (MFMA B-operand layout), softmax scale folded in ----
  const float cf = 0.18033688011112042f;   // log2(e) / temperature(8)
  bf16x8 qf[2];
  {
    const float* qrow = Qg + ((size_t)(batch * SQ + q0 + c)) * DH + g * 8;
#pragma unroll
    for (int dh = 0; dh < 2; ++dh) {
      const float4 a = *(const float4*)(qrow + dh * 32);
      const float4 b = *(const float4*)(qrow + dh * 32 + 4);
      bf16x8 t;
      t[0] = (__bf16)(a.x * cf); t[1] = (__bf16)(a.y * cf);
      t[2] = (__bf16)(a.z * cf); t[3] = (__bf16)(a.w * cf);
      t[4] = (__bf16)(b.x * cf); t[5] = (__bf16)(b.y * cf);
      t[6] = (__bf16)(b.z * cf); t[7] = (__bf16)(b.w * cf);
      qf[dh] = t;
    }
  }

  f32x4 acc[4] = {};            // acc[t][r] = O^T[16t+4g+r][q0+c]
  float m = -INFINITY, l = 0.f;

  const float* kbase = Kg + (size_t)batch * SQ * DH;
  const int row0 = (tid >> 4) << 2;   // staging: 4x4 sub-block per thread
  const int col0 = (tid & 15) << 2;

  for (int kt = 0; kt < SQ / KBLK; ++kt) {
    const int k0 = kt * KBLK;
    __syncthreads();   // previous tile's readers done
    // ---- stage K tile: Ks row-major + Kts transposed, bf16 ----
    {
      float4 v[4];
#pragma unroll
      for (int rr = 0; rr < 4; ++rr)
        v[rr] = *(const float4*)(kbase + (size_t)(k0 + row0 + rr) * DH + col0);
      unsigned short u[4][4];
#pragma unroll
      for (int rr = 0; rr < 4; ++rr) {
        u[rr][0] = f2bf(v[rr].x); u[rr][1] = f2bf(v[rr].y);
        u[rr][2] = f2bf(v[rr].z); u[rr][3] = f2bf(v[rr].w);
      }
#pragma unroll
      for (int rr = 0; rr < 4; ++rr)
        *(ushort4*)&lds.s.Ks[row0 + rr][col0] =
            make_ushort4(u[rr][0], u[rr][1], u[rr][2], u[rr][3]);
#pragma unroll
      for (int i = 0; i < 4; ++i)
        *(ushort4*)&lds.s.Kts[col0 + i][row0] =
            make_ushort4(u[0][i], u[1][i], u[2][i], u[3][i]);
    }
    __syncthreads();

    // ---- QK^T (swapped): S^T[k][q] = sum_d K[k][d] * Q'[q][d] ----
    f32x4 st[4];
#pragma unroll
    for (int sub = 0; sub < 4; ++sub) {
      bf16x8 kf0 = *(const bf16x8*)&lds.s.Ks[sub * 16 + c][g * 8];
      bf16x8 kf1 = *(const bf16x8*)&lds.s.Ks[sub * 16 + c][32 + g * 8];
      f32x4 z = {};
      z = __builtin_amdgcn_mfma_f32_16x16x32_bf16(kf0, qf[0], z, 0, 0, 0);
      z = __builtin_amdgcn_mfma_f32_16x16x32_bf16(kf1, qf[1], z, 0, 0, 0);
      st[sub] = z;
    }

    // ---- online softmax over k for row q=c (16 vals/lane + 4-group xor) ----
    float tm = st[0][0];
#pragma unroll
    for (int sub = 0; sub < 4; ++sub)
#pragma unroll
      for (int r = 0; r < 4; ++r) tm = fmaxf(tm, st[sub][r]);
    tm = fmaxf(tm, __shfl_xor(tm, 16));
    tm = fmaxf(tm, __shfl_xor(tm, 32));
    const float mn    = fmaxf(m, tm);
    const float alpha = exp2f(m - mn);
    m = mn;

    float ts = 0.f;
    unsigned short pu[4][4];
#pragma unroll
    for (int sub = 0; sub < 4; ++sub)
#pragma unroll
      for (int r = 0; r < 4; ++r) {
        const float p = exp2f(st[sub][r] - mn);
        ts += p;
        pu[sub][r] = f2bf(p);
      }
    ts += __shfl_xor(ts, 16);
    ts += __shfl_xor(ts, 32);
    l = l * alpha + ts;
#pragma unroll
    for (int t = 0; t < 4; ++t) {
      acc[t][0] *= alpha; acc[t][1] *= alpha;
      acc[t][2] *= alpha; acc[t][3] *= alpha;
    }

    // ---- P^T write: lane's k = sub*16 + 4g + r are contiguous -> b64 ----
#pragma unroll
    for (int sub = 0; sub < 4; ++sub)
      *(ushort4*)&lds.s.Ps[wave][c][sub * 16 + g * 4] =
          make_ushort4(pu[sub][0], pu[sub][1], pu[sub][2], pu[sub][3]);

    // ---- PV: O^T[d][q] += sum_k K^T[d][k] P^T[k][q] ----
#pragma unroll
    for (int kk = 0; kk < 2; ++kk) {
      bf16x8 pf = *(const bf16x8*)&lds.s.Ps[wave][c][kk * 32 + g * 8];
#pragma unroll
      for (int t = 0; t < 4; ++t) {
        bf16x8 ktf = *(const bf16x8*)&lds.s.Kts[t * 16 + c][kk * 32 + g * 8];
        acc[t] = __builtin_amdgcn_mfma_f32_16x16x32_bf16(ktf, pf, acc[t], 0, 0, 0);
      }
    }
  }

  // ---- epilogue: normalize, transpose O^T -> O via LDS, coalesced store ----
  __syncthreads();   // all waves done with Ks/Kts/Ps before aliasing as Osc
  const float rl = 1.0f / l;
#pragma unroll
  for (int t = 0; t < 4; ++t)
#pragma unroll
    for (int r = 0; r < 4; ++r)
      lds.Osc[wave][c][t * 16 + g * 4 + r] = acc[t][r] * rl;

  const int orow = lane >> 2;
  const int oc   = (lane & 3) * 16;
  float* og = Og + ((size_t)(batch * SQ + qt * QBLK + wave * 16 + orow)) * DH + oc;
#pragma unroll
  for (int u2 = 0; u2 < 4; ++u2) {
    float4 val = *(const float4*)&lds.Osc[wave][orow][oc + u2 * 4];
    *(float4*)(og + u2 * 4) = val;
  }
}

extern "C" void kernel_launch(void* const* d_in, const int* in_sizes, int n_in,
                              void* d_out, int out_size, void* d_ws, size_t ws_size,
                              hipStream_t stream) {
  const float* Q = (const float*)d_in[0];
  const float* K = (const float*)d_in[1];
  // d_in[2] (V) intentionally unused: reference multiplies weights by K.
  float* O = (float*)d_out;
  dim3 grid(NB * (SQ / QBLK));
  attn_fwd<<<grid, 256, 0, stream>>>(Q, K, O);
}

// Round 2
// 87.165 us; speedup vs baseline: 1.6178x; 1.6178x over previous
//
#include <hip/hip_runtime.h>
#include <hip/hip_bf16.h>

// ScaledDotProductAttention: B=4, S=4096, D=64, fp32 in/out.
// scores = Q@K^T / 8; softmax; out = weights @ K  (K, not V -- per reference).
// bf16-MFMA flash attention + split-K (flash-decoding) for occupancy.

#define SQ   4096
#define DH   64
#define NB   4
#define QBLK 64     // q rows per block = 4 waves x 16
#define KBLK 64     // k rows per LDS tile
#define KS_STRIDE 72   // bf16; writes & reads bank-min on this mapping
#define KT_STRIDE 68   // bf16; transposed writes AND PV b128 reads bank-min
#define PS_STRIDE 72
#define OS_STRIDE 68   // fp32 epilogue transpose scratch

typedef __bf16 bf16x8 __attribute__((ext_vector_type(8)));
typedef float  f32x4  __attribute__((ext_vector_type(4)));

union LdsU {
  struct {
    unsigned short Ks [KBLK][KS_STRIDE];   // K[k][d]   bf16
    unsigned short Kts[DH  ][KT_STRIDE];   // K^T[d][k] bf16
    unsigned short Ps [4][16][PS_STRIDE];  // per-wave P[q][k] bf16
  } s;
  float Osc[4][16][OS_STRIDE];             // epilogue transpose scratch
};

__device__ __forceinline__ unsigned short f2bf(float f) {
  return __builtin_bit_cast(unsigned short, (__bf16)f);
}

template <int NS, bool FINAL>
__global__ __launch_bounds__(256, 4)
void attn_fwd(const float* __restrict__ Qg, const float* __restrict__ Kg,
              float* __restrict__ Og, float* __restrict__ Uws,
              float* __restrict__ MLws) {
  __shared__ LdsU lds;
  const int tid  = threadIdx.x;
  const int wave = tid >> 6;
  const int lane = tid & 63;
  const int g    = lane >> 4;
  const int c    = lane & 15;

  const int split = blockIdx.x / (NB * (SQ / QBLK));
  const int rem   = blockIdx.x % (NB * (SQ / QBLK));
  const int batch = rem / (SQ / QBLK);
  const int qt    = rem % (SQ / QBLK);
  const int q0    = qt * QBLK + wave * 16;
  constexpr int NT = (SQ / NS) / KBLK;    // k-tiles per block

  // ---- Q fragments (MFMA B-operand layout), softmax scale folded in ----
  const float cf = 0.18033688011112042f;   // log2(e) / temperature(8)
  bf16x8 qf[2];
  {
    const float* qrow = Qg + ((size_t)(batch * SQ + q0 + c)) * DH + g * 8;
#pragma unroll
    for (int dh = 0; dh < 2; ++dh) {
      const float4 a = *(const float4*)(qrow + dh * 32);
      const float4 b = *(const float4*)(qrow + dh * 32 + 4);
      bf16x8 t;
      t[0] = (__bf16)(a.x * cf); t[1] = (__bf16)(a.y * cf);
      t[2] = (__bf16)(a.z * cf); t[3] = (__bf16)(a.w * cf);
      t[4] = (__bf16)(b.x * cf); t[5] = (__bf16)(b.y * cf);
      t[6] = (__bf16)(b.z * cf); t[7] = (__bf16)(b.w * cf);
      qf[dh] = t;
    }
  }

  f32x4 acc[4] = {};            // acc[t][r] = O^T[16t+4g+r][q0+c]
  float m = -INFINITY, l = 0.f;

  const float* kbase = Kg + (size_t)batch * SQ * DH + (size_t)split * (SQ / NS) * DH;
  const int row0 = (tid >> 4) << 2;   // staging: 4x4 sub-block per thread
  const int col0 = (tid & 15) << 2;

  // prefetch tile 0 into registers
  float4 v[4];
#pragma unroll
  for (int rr = 0; rr < 4; ++rr)
    v[rr] = *(const float4*)(kbase + (size_t)(row0 + rr) * DH + col0);

  for (int kt = 0; kt < NT; ++kt) {
    __syncthreads();   // previous tile's readers done
    // ---- stage K tile from regs: Ks row-major + Kts transposed, bf16 ----
    {
      unsigned short u[4][4];
#pragma unroll
      for (int rr = 0; rr < 4; ++rr) {
        u[rr][0] = f2bf(v[rr].x); u[rr][1] = f2bf(v[rr].y);
        u[rr][2] = f2bf(v[rr].z); u[rr][3] = f2bf(v[rr].w);
      }
#pragma unroll
      for (int rr = 0; rr < 4; ++rr)
        *(ushort4*)&lds.s.Ks[row0 + rr][col0] =
            make_ushort4(u[rr][0], u[rr][1], u[rr][2], u[rr][3]);
#pragma unroll
      for (int i = 0; i < 4; ++i)
        *(ushort4*)&lds.s.Kts[col0 + i][row0] =
            make_ushort4(u[0][i], u[1][i], u[2][i], u[3][i]);
    }
    __syncthreads();

    // ---- issue next tile's global loads; they overlap compute below ----
    if (kt + 1 < NT) {
      const float* nb = kbase + (size_t)(kt + 1) * KBLK * DH;
#pragma unroll
      for (int rr = 0; rr < 4; ++rr)
        v[rr] = *(const float4*)(nb + (size_t)(row0 + rr) * DH + col0);
    }

    // ---- QK^T (swapped): S^T[k][q] = sum_d K[k][d] * Q'[q][d] ----
    f32x4 st[4];
#pragma unroll
    for (int sub = 0; sub < 4; ++sub) {
      bf16x8 kf0 = *(const bf16x8*)&lds.s.Ks[sub * 16 + c][g * 8];
      bf16x8 kf1 = *(const bf16x8*)&lds.s.Ks[sub * 16 + c][32 + g * 8];
      f32x4 z = {};
      z = __builtin_amdgcn_mfma_f32_16x16x32_bf16(kf0, qf[0], z, 0, 0, 0);
      z = __builtin_amdgcn_mfma_f32_16x16x32_bf16(kf1, qf[1], z, 0, 0, 0);
      st[sub] = z;
    }

    // ---- online softmax over k for row q=c ----
    float tm = st[0][0];
#pragma unroll
    for (int sub = 0; sub < 4; ++sub)
#pragma unroll
      for (int r = 0; r < 4; ++r) tm = fmaxf(tm, st[sub][r]);
    tm = fmaxf(tm, __shfl_xor(tm, 16));
    tm = fmaxf(tm, __shfl_xor(tm, 32));
    const float mn    = fmaxf(m, tm);
    const float alpha = exp2f(m - mn);
    m = mn;

    float ts = 0.f;
    unsigned short pu[4][4];
#pragma unroll
    for (int sub = 0; sub < 4; ++sub)
#pragma unroll
      for (int r = 0; r < 4; ++r) {
        const float p = exp2f(st[sub][r] - mn);
        ts += p;
        pu[sub][r] = f2bf(p);
      }
    ts += __shfl_xor(ts, 16);
    ts += __shfl_xor(ts, 32);
    l = l * alpha + ts;
#pragma unroll
    for (int t = 0; t < 4; ++t) {
      acc[t][0] *= alpha; acc[t][1] *= alpha;
      acc[t][2] *= alpha; acc[t][3] *= alpha;
    }

    // ---- P^T write: lane's k = sub*16 + 4g + r contiguous -> b64 ----
#pragma unroll
    for (int sub = 0; sub < 4; ++sub)
      *(ushort4*)&lds.s.Ps[wave][c][sub * 16 + g * 4] =
          make_ushort4(pu[sub][0], pu[sub][1], pu[sub][2], pu[sub][3]);

    // ---- PV: O^T[d][q] += sum_k K^T[d][k] P^T[k][q] ----
#pragma unroll
    for (int kk = 0; kk < 2; ++kk) {
      bf16x8 pf = *(const bf16x8*)&lds.s.Ps[wave][c][kk * 32 + g * 8];
#pragma unroll
      for (int t = 0; t < 4; ++t) {
        bf16x8 ktf = *(const bf16x8*)&lds.s.Kts[t * 16 + c][kk * 32 + g * 8];
        acc[t] = __builtin_amdgcn_mfma_f32_16x16x32_bf16(ktf, pf, acc[t], 0, 0, 0);
      }
    }
  }

  // ---- epilogue: transpose O^T -> row-major via LDS, coalesced store ----
  __syncthreads();   // all waves done reading Ks/Kts/Ps before aliasing as Osc
  const float scale = FINAL ? (1.0f / l) : 1.0f;
#pragma unroll
  for (int t = 0; t < 4; ++t)
#pragma unroll
    for (int r = 0; r < 4; ++r)
      lds.Osc[wave][c][t * 16 + g * 4 + r] = acc[t][r] * scale;

  const int orow = lane >> 2;
  const int oc   = (lane & 3) * 16;
  float* ob;
  if (FINAL) {
    ob = Og + ((size_t)(batch * SQ + qt * QBLK + wave * 16 + orow)) * DH + oc;
  } else {
    ob = Uws + ((size_t)((split * NB + batch) * SQ) + qt * QBLK + wave * 16 + orow) * DH + oc;
  }
#pragma unroll
  for (int u2 = 0; u2 < 4; ++u2) {
    float4 val = *(const float4*)&lds.Osc[wave][orow][oc + u2 * 4];
    *(float4*)(ob + u2 * 4) = val;
  }

  if (!FINAL && g == 0) {
    const size_t row = (size_t)(split * NB + batch) * SQ + q0 + c;
    MLws[row] = m;
    MLws[(size_t)NS * NB * SQ + row] = l;
  }
}

template <int NS>
__global__ __launch_bounds__(256, 4)
void combine_splits(const float* __restrict__ U, const float* __restrict__ ML,
                    float* __restrict__ O) {
  const int idx = blockIdx.x * 256 + threadIdx.x;   // NB*SQ*16 threads
  const int row = idx >> 4;                          // batch*SQ + q
  const int d4  = (idx & 15) << 2;
  const int RT  = NB * SQ;

  float mi[NS], li[NS];
#pragma unroll
  for (int i = 0; i < NS; ++i) {
    mi[i] = ML[(size_t)i * RT + row];
    li[i] = ML[(size_t)(NS + i) * RT + row];
  }
  float M = mi[0];
#pragma unroll
  for (int i = 1; i < NS; ++i) M = fmaxf(M, mi[i]);
  float den = 0.f, w[NS];
#pragma unroll
  for (int i = 0; i < NS; ++i) {
    w[i] = exp2f(mi[i] - M);
    den += li[i] * w[i];
  }
  const float rden = 1.0f / den;
  float4 o = make_float4(0.f, 0.f, 0.f, 0.f);
#pragma unroll
  for (int i = 0; i < NS; ++i) {
    const float4 u = *(const float4*)&U[((size_t)i * RT + row) * DH + d4];
    o.x += w[i] * u.x; o.y += w[i] * u.y;
    o.z += w[i] * u.z; o.w += w[i] * u.w;
  }
  o.x *= rden; o.y *= rden; o.z *= rden; o.w *= rden;
  *(float4*)&O[(size_t)row * DH + d4] = o;
}

extern "C" void kernel_launch(void* const* d_in, const int* in_sizes, int n_in,
                              void* d_out, int out_size, void* d_ws, size_t ws_size,
                              hipStream_t stream) {
  const float* Q = (const float*)d_in[0];
  const float* K = (const float*)d_in[1];
  // d_in[2] (V) intentionally unused: reference multiplies weights by K.
  float* O = (float*)d_out;

  constexpr int NS = 4;
  const size_t need = (size_t)NS * NB * SQ * (DH + 2) * sizeof(float);
  if (ws_size >= need) {
    float* U  = (float*)d_ws;
    float* ML = U + (size_t)NS * NB * SQ * DH;
    attn_fwd<NS, false><<<dim3(NS * NB * (SQ / QBLK)), 256, 0, stream>>>(Q, K, nullptr, U, ML);
    combine_splits<NS><<<dim3((NB * SQ * 16) / 256), 256, 0, stream>>>(U, ML, O);
  } else {
    attn_fwd<1, true><<<dim3(NB * (SQ / QBLK)), 256, 0, stream>>>(Q, K, O, nullptr, nullptr);
  }
}

// Round 3
// 58.050 us; speedup vs baseline: 2.4292x; 1.5016x over previous
//
#include <hip/hip_runtime.h>
#include <hip/hip_bf16.h>

// ScaledDotProductAttention: B=4, S=4096, D=64, fp32 in/out.
// scores = Q@K^T / 8; softmax; out = weights @ K  (K, not V -- per reference).
// 32x32x16 bf16 MFMA flash attention, 32 q/wave, in-register P (cvt_pk +
// permlane32_swap), double-buffered K tiles (1 barrier/tile), split-K.

#define SQ   4096
#define DH   64
#define NB   4
#define QBLK 128    // q rows per block = 4 waves x 32
#define KBLK 64     // k rows per LDS tile
#define KS_STRIDE 72   // bf16; all access patterns bank-minimal (derived)
#define KT_STRIDE 68
#define OS_STRIDE 66   // fp32 epilogue scratch

typedef __bf16 bf16x8 __attribute__((ext_vector_type(8)));
typedef float  f32x16 __attribute__((ext_vector_type(16)));
typedef unsigned int u32x4 __attribute__((ext_vector_type(4)));

union LdsU {
  struct {
    unsigned short Ks[2][KBLK][KS_STRIDE];  // K[k][d], double-buffered
    unsigned short Kt[2][DH][KT_STRIDE];    // K^T[d][k], double-buffered
  } s;                                      // 35840 B
  float Osc[4][32][OS_STRIDE];              // epilogue transpose (33792 B)
};

__device__ __forceinline__ unsigned short f2bf(float f) {
  return __builtin_bit_cast(unsigned short, (__bf16)f);
}

template <int NS, bool FINAL>
__global__ __launch_bounds__(256, 4)
void attn_fwd(const float* __restrict__ Qg, const float* __restrict__ Kg,
              float* __restrict__ Og, float* __restrict__ Uws,
              float* __restrict__ MLws) {
  __shared__ LdsU lds;
  const int tid  = threadIdx.x;
  const int wave = tid >> 6;
  const int lane = tid & 63;
  const int c32  = lane & 31;   // MFMA row/col index
  const int h    = lane >> 5;   // lane half

  constexpr int QT = SQ / QBLK;            // 32 q-tiles
  const int split = blockIdx.x / (NB * QT);
  const int rem   = blockIdx.x % (NB * QT);
  const int batch = rem / QT;
  const int qt    = rem % QT;
  const int q0w   = qt * QBLK + wave * 32;
  constexpr int NT = (SQ / NS) / KBLK;

  // ---- Q fragments (B-operand: lane holds Q[q=c32][d=16dc+8h+j]) ----
  const float cf = 0.18033688011112042f;   // log2(e)/8
  bf16x8 qf[4];
  {
    const float* qrow = Qg + ((size_t)(batch * SQ + q0w + c32)) * DH + 8 * h;
#pragma unroll
    for (int dc = 0; dc < 4; ++dc) {
      const float4 a = *(const float4*)(qrow + dc * 16);
      const float4 b = *(const float4*)(qrow + dc * 16 + 4);
      bf16x8 t;
      t[0] = (__bf16)(a.x * cf); t[1] = (__bf16)(a.y * cf);
      t[2] = (__bf16)(a.z * cf); t[3] = (__bf16)(a.w * cf);
      t[4] = (__bf16)(b.x * cf); t[5] = (__bf16)(b.y * cf);
      t[6] = (__bf16)(b.z * cf); t[7] = (__bf16)(b.w * cf);
      qf[dc] = t;
    }
  }

  f32x16 acc0 = {};   // O^T[d = (r&3)+8(r>>2)+4h     ][q = c32]
  f32x16 acc1 = {};   // O^T[d = 32 + (r&3)+8(r>>2)+4h][q = c32]
  float m = -INFINITY, l = 0.f;

  const float* kbase = Kg + (size_t)batch * SQ * DH + (size_t)split * (SQ / NS) * DH;
  const int row0 = (tid >> 4) << 2;
  const int col0 = (tid & 15) << 2;

  float4 v[4];   // register-staged K tile (4x4 f32 per thread)
#pragma unroll
  for (int rr = 0; rr < 4; ++rr)
    v[rr] = *(const float4*)(kbase + (size_t)(row0 + rr) * DH + col0);

  for (int kt = 0; kt < NT; ++kt) {
    const int bsel = kt & 1;
    // ---- stage tile kt from regs into buffer bsel (dbuf: no read hazard) ----
    {
      unsigned short u[4][4];
#pragma unroll
      for (int rr = 0; rr < 4; ++rr) {
        u[rr][0] = f2bf(v[rr].x); u[rr][1] = f2bf(v[rr].y);
        u[rr][2] = f2bf(v[rr].z); u[rr][3] = f2bf(v[rr].w);
      }
#pragma unroll
      for (int rr = 0; rr < 4; ++rr)
        *(ushort4*)&lds.s.Ks[bsel][row0 + rr][col0] =
            make_ushort4(u[rr][0], u[rr][1], u[rr][2], u[rr][3]);
#pragma unroll
      for (int i = 0; i < 4; ++i)
        *(ushort4*)&lds.s.Kt[bsel][col0 + i][row0] =
            make_ushort4(u[0][i], u[1][i], u[2][i], u[3][i]);
    }
    __syncthreads();   // the ONLY barrier per tile

    // ---- prefetch next tile (after barrier: no vmcnt in barrier drain) ----
    if (kt + 1 < NT) {
      const float* nb = kbase + (size_t)(kt + 1) * KBLK * DH;
#pragma unroll
      for (int rr = 0; rr < 4; ++rr)
        v[rr] = *(const float4*)(nb + (size_t)(row0 + rr) * DH + col0);
    }

    // ---- QK^T: S^T[k][q], two 32-k blocks ----
    f32x16 s0 = {}, s1 = {};
#pragma unroll
    for (int dc = 0; dc < 4; ++dc) {
      bf16x8 kf0 = *(const bf16x8*)&lds.s.Ks[bsel][c32][dc * 16 + 8 * h];
      bf16x8 kf1 = *(const bf16x8*)&lds.s.Ks[bsel][32 + c32][dc * 16 + 8 * h];
      s0 = __builtin_amdgcn_mfma_f32_32x32x16_bf16(kf0, qf[dc], s0, 0, 0, 0);
      s1 = __builtin_amdgcn_mfma_f32_32x32x16_bf16(kf1, qf[dc], s1, 0, 0, 0);
    }

    // ---- online softmax (row q=c32; halves combined via xor-32) ----
    float tm = s0[0];
#pragma unroll
    for (int r = 1; r < 16; ++r) tm = fmaxf(tm, s0[r]);
#pragma unroll
    for (int r = 0; r < 16; ++r) tm = fmaxf(tm, s1[r]);
    tm = fmaxf(tm, __shfl_xor(tm, 32));

    if (__any(tm > m + 8.f)) {       // defer-max: skip rescale when bounded
      const float mn    = fmaxf(m, tm);
      const float alpha = exp2f(m - mn);
      m = mn;
      l *= alpha;
#pragma unroll
      for (int r = 0; r < 16; ++r) { acc0[r] *= alpha; acc1[r] *= alpha; }
    }

    float ts = 0.f;
#pragma unroll
    for (int r = 0; r < 16; ++r) { s0[r] = exp2f(s0[r] - m); ts += s0[r]; }
#pragma unroll
    for (int r = 0; r < 16; ++r) { s1[r] = exp2f(s1[r] - m); ts += s1[r]; }
    ts += __shfl_xor(ts, 32);
    l += ts;

    // ---- P -> bf16 B-fragments in-register; PV per 32-k block ----
#pragma unroll
    for (int kb = 0; kb < 2; ++kb) {
      const f32x16 sv = kb ? s1 : s0;
      unsigned int dw[8];
#pragma unroll
      for (int d = 0; d < 8; ++d)
        asm("v_cvt_pk_bf16_f32 %0, %1, %2"
            : "=v"(dw[d]) : "v"(sv[2 * d]), "v"(sv[2 * d + 1]));
      // swap halves: a' = [a.lo|b.lo], b' = [a.hi|b.hi]
      asm("v_permlane32_swap_b32 %0, %1" : "+v"(dw[0]), "+v"(dw[2]));
      asm("v_permlane32_swap_b32 %0, %1" : "+v"(dw[1]), "+v"(dw[3]));
      asm("v_permlane32_swap_b32 %0, %1" : "+v"(dw[4]), "+v"(dw[6]));
      asm("v_permlane32_swap_b32 %0, %1" : "+v"(dw[5]), "+v"(dw[7]));
      u32x4 w0 = {dw[0], dw[1], dw[2], dw[3]};
      u32x4 w1 = {dw[4], dw[5], dw[6], dw[7]};
      const bf16x8 pb0 = __builtin_bit_cast(bf16x8, w0);   // k-half 0
      const bf16x8 pb1 = __builtin_bit_cast(bf16x8, w1);   // k-half 1
#pragma unroll
      for (int kh = 0; kh < 2; ++kh) {
        const bf16x8 pb = kh ? pb1 : pb0;
        bf16x8 kt0 = *(const bf16x8*)&lds.s.Kt[bsel][c32][kb * 32 + kh * 16 + 8 * h];
        bf16x8 kt1 = *(const bf16x8*)&lds.s.Kt[bsel][32 + c32][kb * 32 + kh * 16 + 8 * h];
        acc0 = __builtin_amdgcn_mfma_f32_32x32x16_bf16(kt0, pb, acc0, 0, 0, 0);
        acc1 = __builtin_amdgcn_mfma_f32_32x32x16_bf16(kt1, pb, acc1, 0, 0, 0);
      }
    }
  }

  // ---- epilogue: O^T -> row-major via LDS, coalesced stores ----
  __syncthreads();   // all waves done with K buffers before aliasing as Osc
  const float scale = FINAL ? (1.0f / l) : 1.0f;
#pragma unroll
  for (int mm = 0; mm < 4; ++mm) {
    float4 w0 = make_float4(acc0[4 * mm] * scale, acc0[4 * mm + 1] * scale,
                            acc0[4 * mm + 2] * scale, acc0[4 * mm + 3] * scale);
    float4 w1 = make_float4(acc1[4 * mm] * scale, acc1[4 * mm + 1] * scale,
                            acc1[4 * mm + 2] * scale, acc1[4 * mm + 3] * scale);
    *(float4*)&lds.Osc[wave][c32][8 * mm + 4 * h]      = w0;
    *(float4*)&lds.Osc[wave][c32][32 + 8 * mm + 4 * h] = w1;
  }
  __syncthreads();

  float* obase = FINAL
      ? (Og + ((size_t)(batch * SQ) + q0w) * DH)
      : (Uws + ((size_t)((split * NB + batch) * SQ) + q0w) * DH);
#pragma unroll
  for (int u = 0; u < 8; ++u) {
    const int qr = 4 * u + (lane >> 4);
    float4 val = *(const float4*)&lds.Osc[wave][qr][4 * (lane & 15)];
    *(float4*)(obase + (size_t)qr * DH + 4 * (lane & 15)) = val;
  }

  if (!FINAL && h == 0) {
    const size_t row = (size_t)(split * NB + batch) * SQ + q0w + c32;
    MLws[row] = m;
    MLws[(size_t)NS * NB * SQ + row] = l;
  }
}

template <int NS>
__global__ __launch_bounds__(256, 4)
void combine_splits(const float* __restrict__ U, const float* __restrict__ ML,
                    float* __restrict__ O) {
  const int idx = blockIdx.x * 256 + threadIdx.x;   // NB*SQ*16 threads
  const int row = idx >> 4;
  const int d4  = (idx & 15) << 2;
  const int RT  = NB * SQ;

  float mi[NS], li[NS];
#pragma unroll
  for (int i = 0; i < NS; ++i) {
    mi[i] = ML[(size_t)i * RT + row];
    li[i] = ML[(size_t)(NS + i) * RT + row];
  }
  float M = mi[0];
#pragma unroll
  for (int i = 1; i < NS; ++i) M = fmaxf(M, mi[i]);
  float den = 0.f, w[NS];
#pragma unroll
  for (int i = 0; i < NS; ++i) {
    w[i] = exp2f(mi[i] - M);
    den += li[i] * w[i];
  }
  const float rden = 1.0f / den;
  float4 o = make_float4(0.f, 0.f, 0.f, 0.f);
#pragma unroll
  for (int i = 0; i < NS; ++i) {
    const float4 u = *(const float4*)&U[((size_t)i * RT + row) * DH + d4];
    o.x += w[i] * u.x; o.y += w[i] * u.y;
    o.z += w[i] * u.z; o.w += w[i] * u.w;
  }
  o.x *= rden; o.y *= rden; o.z *= rden; o.w *= rden;
  *(float4*)&O[(size_t)row * DH + d4] = o;
}

extern "C" void kernel_launch(void* const* d_in, const int* in_sizes, int n_in,
                              void* d_out, int out_size, void* d_ws, size_t ws_size,
                              hipStream_t stream) {
  const float* Q = (const float*)d_in[0];
  const float* K = (const float*)d_in[1];
  // d_in[2] (V) intentionally unused: reference multiplies weights by K.
  float* O = (float*)d_out;

  auto need = [](int ns) {
    return (size_t)ns * NB * SQ * (DH + 2) * sizeof(float);
  };
  if (ws_size >= need(8)) {
    constexpr int NS = 8;
    float* U  = (float*)d_ws;
    float* ML = U + (size_t)NS * NB * SQ * DH;
    attn_fwd<NS, false><<<dim3(NS * NB * (SQ / QBLK)), 256, 0, stream>>>(Q, K, nullptr, U, ML);
    combine_splits<NS><<<dim3((NB * SQ * 16) / 256), 256, 0, stream>>>(U, ML, O);
  } else if (ws_size >= need(4)) {
    constexpr int NS = 4;
    float* U  = (float*)d_ws;
    float* ML = U + (size_t)NS * NB * SQ * DH;
    attn_fwd<NS, false><<<dim3(NS * NB * (SQ / QBLK)), 256, 0, stream>>>(Q, K, nullptr, U, ML);
    combine_splits<NS><<<dim3((NB * SQ * 16) / 256), 256, 0, stream>>>(U, ML, O);
  } else {
    attn_fwd<1, true><<<dim3(NB * (SQ / QBLK)), 256, 0, stream>>>(Q, K, O, nullptr, nullptr);
  }
}

// Round 4
// 57.674 us; speedup vs baseline: 2.4450x; 1.0065x over previous
//
#include <hip/hip_runtime.h>
#include <hip/hip_bf16.h>

// ScaledDotProductAttention: B=4, S=4096, D=64, fp32 in/out.
// scores = Q@K^T / 8; softmax; out = weights @ K  (K, not V -- per reference).
// 32x32x16 bf16 MFMA flash attention, 32 q/wave, in-register P (cvt_pk +
// permlane32_swap), double-buffered K tiles (1 barrier/tile), split-K.

#define SQ   4096
#define DH   64
#define NB   4
#define QBLK 128    // q rows per block = 4 waves x 32
#define KBLK 64     // k rows per LDS tile
#define KS_STRIDE 72   // bf16; all access patterns bank-minimal (derived)
#define KT_STRIDE 68
#define OS_STRIDE 66   // fp32 epilogue scratch

typedef __bf16 bf16x8 __attribute__((ext_vector_type(8)));
typedef float  f32x16 __attribute__((ext_vector_type(16)));
typedef unsigned int u32x4 __attribute__((ext_vector_type(4)));

union LdsU {
  struct {
    unsigned short Ks[2][KBLK][KS_STRIDE];  // K[k][d], double-buffered
    unsigned short Kt[2][DH][KT_STRIDE];    // K^T[d][k], double-buffered
  } s;                                      // 35840 B
  float Osc[4][32][OS_STRIDE];              // epilogue transpose (33792 B)
};

__device__ __forceinline__ unsigned short f2bf(float f) {
  return __builtin_bit_cast(unsigned short, (__bf16)f);
}

template <int NS, bool FINAL>
__global__ __launch_bounds__(256, 4)
void attn_fwd(const float* __restrict__ Qg, const float* __restrict__ Kg,
              float* __restrict__ Og, float* __restrict__ Uws,
              float* __restrict__ MLws) {
  __shared__ LdsU lds;
  const int tid  = threadIdx.x;
  const int wave = tid >> 6;
  const int lane = tid & 63;
  const int c32  = lane & 31;   // MFMA row/col index
  const int h    = lane >> 5;   // lane half

  constexpr int QT = SQ / QBLK;            // 32 q-tiles
  const int split = blockIdx.x / (NB * QT);
  const int rem   = blockIdx.x % (NB * QT);
  const int batch = rem / QT;
  const int qt    = rem % QT;
  const int q0w   = qt * QBLK + wave * 32;
  constexpr int NT = (SQ / NS) / KBLK;

  // ---- Q fragments (B-operand: lane holds Q[q=c32][d=16dc+8h+j]) ----
  const float cf = 0.18033688011112042f;   // log2(e)/8
  bf16x8 qf[4];
  {
    const float* qrow = Qg + ((size_t)(batch * SQ + q0w + c32)) * DH + 8 * h;
#pragma unroll
    for (int dc = 0; dc < 4; ++dc) {
      const float4 a = *(const float4*)(qrow + dc * 16);
      const float4 b = *(const float4*)(qrow + dc * 16 + 4);
      bf16x8 t;
      t[0] = (__bf16)(a.x * cf); t[1] = (__bf16)(a.y * cf);
      t[2] = (__bf16)(a.z * cf); t[3] = (__bf16)(a.w * cf);
      t[4] = (__bf16)(b.x * cf); t[5] = (__bf16)(b.y * cf);
      t[6] = (__bf16)(b.z * cf); t[7] = (__bf16)(b.w * cf);
      qf[dc] = t;
    }
  }

  f32x16 acc0 = {};   // O^T[d = (r&3)+8(r>>2)+4h     ][q = c32]
  f32x16 acc1 = {};   // O^T[d = 32 + (r&3)+8(r>>2)+4h][q = c32]
  float m = -INFINITY, l = 0.f;

  const float* kbase = Kg + (size_t)batch * SQ * DH + (size_t)split * (SQ / NS) * DH;
  const int row0 = (tid >> 4) << 2;
  const int col0 = (tid & 15) << 2;

  float4 v[4];   // register-staged K tile (4x4 f32 per thread)
#pragma unroll
  for (int rr = 0; rr < 4; ++rr)
    v[rr] = *(const float4*)(kbase + (size_t)(row0 + rr) * DH + col0);

  for (int kt = 0; kt < NT; ++kt) {
    const int bsel = kt & 1;
    // ---- stage tile kt from regs into buffer bsel (dbuf: no read hazard) ----
    {
      unsigned short u[4][4];
#pragma unroll
      for (int rr = 0; rr < 4; ++rr) {
        u[rr][0] = f2bf(v[rr].x); u[rr][1] = f2bf(v[rr].y);
        u[rr][2] = f2bf(v[rr].z); u[rr][3] = f2bf(v[rr].w);
      }
#pragma unroll
      for (int rr = 0; rr < 4; ++rr)
        *(ushort4*)&lds.s.Ks[bsel][row0 + rr][col0] =
            make_ushort4(u[rr][0], u[rr][1], u[rr][2], u[rr][3]);
#pragma unroll
      for (int i = 0; i < 4; ++i)
        *(ushort4*)&lds.s.Kt[bsel][col0 + i][row0] =
            make_ushort4(u[0][i], u[1][i], u[2][i], u[3][i]);
    }
    __syncthreads();   // the ONLY barrier per tile

    // ---- prefetch next tile (after barrier: no vmcnt in barrier drain) ----
    if (kt + 1 < NT) {
      const float* nb = kbase + (size_t)(kt + 1) * KBLK * DH;
#pragma unroll
      for (int rr = 0; rr < 4; ++rr)
        v[rr] = *(const float4*)(nb + (size_t)(row0 + rr) * DH + col0);
    }

    // ---- QK^T: S^T[k][q], two 32-k blocks ----
    f32x16 s0 = {}, s1 = {};
#pragma unroll
    for (int dc = 0; dc < 4; ++dc) {
      bf16x8 kf0 = *(const bf16x8*)&lds.s.Ks[bsel][c32][dc * 16 + 8 * h];
      bf16x8 kf1 = *(const bf16x8*)&lds.s.Ks[bsel][32 + c32][dc * 16 + 8 * h];
      s0 = __builtin_amdgcn_mfma_f32_32x32x16_bf16(kf0, qf[dc], s0, 0, 0, 0);
      s1 = __builtin_amdgcn_mfma_f32_32x32x16_bf16(kf1, qf[dc], s1, 0, 0, 0);
    }

    // ---- online softmax (row q=c32; halves combined via xor-32) ----
    float tm = s0[0];
#pragma unroll
    for (int r = 1; r < 16; ++r) tm = fmaxf(tm, s0[r]);
#pragma unroll
    for (int r = 0; r < 16; ++r) tm = fmaxf(tm, s1[r]);
    tm = fmaxf(tm, __shfl_xor(tm, 32));

    if (__any(tm > m + 8.f)) {       // defer-max: skip rescale when bounded
      const float mn    = fmaxf(m, tm);
      const float alpha = exp2f(m - mn);
      m = mn;
      l *= alpha;
#pragma unroll
      for (int r = 0; r < 16; ++r) { acc0[r] *= alpha; acc1[r] *= alpha; }
    }

    float ts = 0.f;
#pragma unroll
    for (int r = 0; r < 16; ++r) { s0[r] = exp2f(s0[r] - m); ts += s0[r]; }
#pragma unroll
    for (int r = 0; r < 16; ++r) { s1[r] = exp2f(s1[r] - m); ts += s1[r]; }
    ts += __shfl_xor(ts, 32);
    l += ts;

    // ---- P -> bf16 B-fragments in-register; PV per 32-k block ----
#pragma unroll
    for (int kb = 0; kb < 2; ++kb) {
      const f32x16 sv = kb ? s1 : s0;
      unsigned int dw[8];
#pragma unroll
      for (int d = 0; d < 8; ++d)
        asm("v_cvt_pk_bf16_f32 %0, %1, %2"
            : "=v"(dw[d]) : "v"(sv[2 * d]), "v"(sv[2 * d + 1]));
      // swap halves: a' = [a.lo|b.lo], b' = [a.hi|b.hi]
      asm("v_permlane32_swap_b32 %0, %1" : "+v"(dw[0]), "+v"(dw[2]));
      asm("v_permlane32_swap_b32 %0, %1" : "+v"(dw[1]), "+v"(dw[3]));
      asm("v_permlane32_swap_b32 %0, %1" : "+v"(dw[4]), "+v"(dw[6]));
      asm("v_permlane32_swap_b32 %0, %1" : "+v"(dw[5]), "+v"(dw[7]));
      u32x4 w0 = {dw[0], dw[1], dw[2], dw[3]};
      u32x4 w1 = {dw[4], dw[5], dw[6], dw[7]};
      const bf16x8 pb0 = __builtin_bit_cast(bf16x8, w0);   // k-half 0
      const bf16x8 pb1 = __builtin_bit_cast(bf16x8, w1);   // k-half 1
#pragma unroll
      for (int kh = 0; kh < 2; ++kh) {
        const bf16x8 pb = kh ? pb1 : pb0;
        bf16x8 kt0 = *(const bf16x8*)&lds.s.Kt[bsel][c32][kb * 32 + kh * 16 + 8 * h];
        bf16x8 kt1 = *(const bf16x8*)&lds.s.Kt[bsel][32 + c32][kb * 32 + kh * 16 + 8 * h];
        acc0 = __builtin_amdgcn_mfma_f32_32x32x16_bf16(kt0, pb, acc0, 0, 0, 0);
        acc1 = __builtin_amdgcn_mfma_f32_32x32x16_bf16(kt1, pb, acc1, 0, 0, 0);
      }
    }
  }

  // ---- epilogue: O^T -> row-major via LDS, coalesced stores ----
  __syncthreads();   // all waves done with K buffers before aliasing as Osc
  const float scale = FINAL ? (1.0f / l) : 1.0f;
#pragma unroll
  for (int mm = 0; mm < 4; ++mm) {
    float4 w0 = make_float4(acc0[4 * mm] * scale, acc0[4 * mm + 1] * scale,
                            acc0[4 * mm + 2] * scale, acc0[4 * mm + 3] * scale);
    float4 w1 = make_float4(acc1[4 * mm] * scale, acc1[4 * mm + 1] * scale,
                            acc1[4 * mm + 2] * scale, acc1[4 * mm + 3] * scale);
    *(float4*)&lds.Osc[wave][c32][8 * mm + 4 * h]      = w0;
    *(float4*)&lds.Osc[wave][c32][32 + 8 * mm + 4 * h] = w1;
  }
  __syncthreads();

  float* obase = FINAL
      ? (Og + ((size_t)(batch * SQ) + q0w) * DH)
      : (Uws + ((size_t)((split * NB + batch) * SQ) + q0w) * DH);
#pragma unroll
  for (int u = 0; u < 8; ++u) {
    const int qr = 4 * u + (lane >> 4);
    float4 val = *(const float4*)&lds.Osc[wave][qr][4 * (lane & 15)];
    *(float4*)(obase + (size_t)qr * DH + 4 * (lane & 15)) = val;
  }

  if (!FINAL && h == 0) {
    const size_t row = (size_t)(split * NB + batch) * SQ + q0w + c32;
    MLws[row] = m;
    MLws[(size_t)NS * NB * SQ + row] = l;
  }
}

template <int NS>
__global__ __launch_bounds__(256, 4)
void combine_splits(const float* __restrict__ U, const float* __restrict__ ML,
                    float* __restrict__ O) {
  const int idx = blockIdx.x * 256 + threadIdx.x;   // NB*SQ*16 threads
  const int row = idx >> 4;
  const int d4  = (idx & 15) << 2;
  const int RT  = NB * SQ;

  float mi[NS], li[NS];
#pragma unroll
  for (int i = 0; i < NS; ++i) {
    mi[i] = ML[(size_t)i * RT + row];
    li[i] = ML[(size_t)(NS + i) * RT + row];
  }
  float M = mi[0];
#pragma unroll
  for (int i = 1; i < NS; ++i) M = fmaxf(M, mi[i]);
  float den = 0.f, w[NS];
#pragma unroll
  for (int i = 0; i < NS; ++i) {
    w[i] = exp2f(mi[i] - M);
    den += li[i] * w[i];
  }
  const float rden = 1.0f / den;
  float4 o = make_float4(0.f, 0.f, 0.f, 0.f);
#pragma unroll
  for (int i = 0; i < NS; ++i) {
    const float4 u = *(const float4*)&U[((size_t)i * RT + row) * DH + d4];
    o.x += w[i] * u.x; o.y += w[i] * u.y;
    o.z += w[i] * u.z; o.w += w[i] * u.w;
  }
  o.x *= rden; o.y *= rden; o.z *= rden; o.w *= rden;
  *(float4*)&O[(size_t)row * DH + d4] = o;
}

extern "C" void kernel_launch(void* const* d_in, const int* in_sizes, int n_in,
                              void* d_out, int out_size, void* d_ws, size_t ws_size,
                              hipStream_t stream) {
  const float* Q = (const float*)d_in[0];
  const float* K = (const float*)d_in[1];
  // d_in[2] (V) intentionally unused: reference multiplies weights by K.
  float* O = (float*)d_out;

  auto need = [](int ns) {
    return (size_t)ns * NB * SQ * (DH + 2) * sizeof(float);
  };
  if (ws_size >= need(8)) {
    constexpr int NS = 8;
    float* U  = (float*)d_ws;
    float* ML = U + (size_t)NS * NB * SQ * DH;
    attn_fwd<NS, false><<<dim3(NS * NB * (SQ / QBLK)), 256, 0, stream>>>(Q, K, nullptr, U, ML);
    combine_splits<NS><<<dim3((NB * SQ * 16) / 256), 256, 0, stream>>>(U, ML, O);
  } else if (ws_size >= need(4)) {
    constexpr int NS = 4;
    float* U  = (float*)d_ws;
    float* ML = U + (size_t)NS * NB * SQ * DH;
    attn_fwd<NS, false><<<dim3(NS * NB * (SQ / QBLK)), 256, 0, stream>>>(Q, K, nullptr, U, ML);
    combine_splits<NS><<<dim3((NB * SQ * 16) / 256), 256, 0, stream>>>(U, ML, O);
  } else {
    attn_fwd<1, true><<<dim3(NB * (SQ / QBLK)), 256, 0, stream>>>(Q, K, O, nullptr, nullptr);
  }
}